// Round 8
// baseline (1306.399 us; speedup 1.0000x reference)
//
#include <hip/hip_runtime.h>
#include <hip/hip_bf16.h>

// MixSoftmax: B=4 S=1024 H=1024 K=8 E=512 C=10000
// out[t,c] = sum_k softmax_k(ctx@prior_w^T)[t,k] * softmax_c(tanh(ctx@latent_w^T)[t,k,:] @ dec_w^T)[c]
//
// R3: m97-style global_load_lds mainloop (16B DMA, linear LDS, 2 barriers/K).
// R4: XOR-swizzle (rule #21) -> bank conflicts 1.24e8 -> 0, MfmaUtil 26->35%.
// R6-R9: chunked P-store path (P=fp16(exp), Z from ROUNDED values, streaming
// combine). Measured: combine-from-L3 confirmed (~4x vs HBM); chunk ramp/tail
// costs ~30-40us per dispatch; L3 does NOT absorb P writes.
// R10 (this round): FAT DISPATCHES — fuse combine(chunk i-1) into
// pass1(chunk i) via grid concat + ping-pong P buffers (2 x 165.7 MB, ws>=723MB
// known from R4). Even blocks = pass1 (compute-bound), odd = combine (memory-
// bound): combine hides in pass1's idle BW (17% busy) and fills ramp/drain.
// Also: priors fused into latent dispatch; 3 cvt kernels merged into 1.

#define BM 128
#define BN 128
#define BK 64

typedef __attribute__((ext_vector_type(8))) short bf16x8;
typedef __attribute__((ext_vector_type(4))) float f32x4;
typedef __attribute__((ext_vector_type(8))) _Float16 f16x8;

typedef const __attribute__((address_space(1))) unsigned int* gas_u32p;
typedef __attribute__((address_space(3))) unsigned int* las_u32p;

__device__ __forceinline__ unsigned short f2bf(float x) {
  union { float f; unsigned int u; } un; un.f = x;
  unsigned int r = un.u + 0x7FFFu + ((un.u >> 16) & 1u);
  return (unsigned short)(r >> 16);
}

// One fused bf16-cast over ctx (1048576 f4), lw (1048576 f4), dw (1280000 f4).
__global__ void k_cvt_all(const float4* __restrict__ ctx, ushort4* __restrict__ ctxb,
                          const float4* __restrict__ lw, ushort4* __restrict__ lwb,
                          const float4* __restrict__ dw, ushort4* __restrict__ dwb) {
  int i = blockIdx.x * 256 + threadIdx.x;
  const float4* s; ushort4* d; int off;
  if (i < 1048576) { s = ctx; d = ctxb; off = i; }
  else if (i < 2097152) { s = lw; d = lwb; off = i - 1048576; }
  else if (i < 3377152) { s = dw; d = dwb; off = i - 2097152; }
  else return;
  float4 v = s[off];
  ushort4 o;
  o.x = f2bf(v.x); o.y = f2bf(v.y); o.z = f2bf(v.z); o.w = f2bf(v.w);
  d[off] = o;
}

// Priors for 4 tokens (one per wave), LDS-free: butterfly xor-reduce leaves the
// full dot in every lane; lane 0 finalizes softmax.
__device__ __forceinline__ void priors_body(int pid, const float* __restrict__ ctx,
                                            const float* __restrict__ pw,
                                            const float* __restrict__ pb,
                                            float* __restrict__ priors) {
  int wave = threadIdx.x >> 6, lane = threadIdx.x & 63;
  int t = pid * 4 + wave;
  const float* c = ctx + (size_t)t * 1024;
  float lg[8];
  #pragma unroll
  for (int k = 0; k < 8; ++k) {
    const float* w = pw + k * 1024;
    float s = 0.f;
    for (int h = lane; h < 1024; h += 64) s += c[h] * w[h];
    #pragma unroll
    for (int m = 1; m <= 32; m <<= 1) s += __shfl_xor(s, m);
    lg[k] = s + pb[k];
  }
  if (lane == 0) {
    float mx = lg[0];
    #pragma unroll
    for (int k = 1; k < 8; ++k) mx = fmaxf(mx, lg[k]);
    float z = 0.f, e[8];
    #pragma unroll
    for (int k = 0; k < 8; ++k) { e[k] = __expf(lg[k] - mx); z += e[k]; }
    float inv = 1.f / z;
    #pragma unroll
    for (int k = 0; k < 8; ++k) priors[(size_t)t * 8 + k] = e[k] * inv;
  }
}

// Shared GEMM mainloop: C[m,n] = A[m,:] . B[n,:]  (both row-major, K contiguous)
// 128x128 tile, 4 waves in 2x2, each wave 64x64 = 4x4 frags of 16x16, BK=64.
// Per K-step: { barrier; 8x global_load_lds(16B, source pre-swizzled);
// barrier (vmcnt0 drain); swizzled ds_read_b128 frags + 32 MFMA }.
// Swizzle: 16B-chunk kc of row r lives at LDS chunk slot kc^(r&7).
__device__ __forceinline__ void gemm_mainloop(
    const unsigned short* __restrict__ A, const unsigned short* __restrict__ B,
    int lda, int ldb, int m0, int n0, int ktiles,
    unsigned short* ldsA, unsigned short* ldsB, f32x4 acc[4][4]) {
  const int tid = threadIdx.x;
  const int lane = tid & 63;
  const int wave = tid >> 6;
  const int wm = wave & 1, wn = wave >> 1;
  const int lrow = lane & 15, lq = lane >> 4;

  for (int kt = 0; kt < ktiles; ++kt) {
    int k0 = kt * BK;
    __syncthreads();   // previous iter's LDS reads complete before DMA overwrites
    #pragma unroll
    for (int p = 0; p < 4; ++p) {
      int chunk = p * 256 + tid;          // 0..1023, 16B each = full 16KB tile
      int row = chunk >> 3, kc = chunk & 7;
      int kcs = kc ^ (row & 7);           // inverse-swizzle the global source
      __builtin_amdgcn_global_load_lds(
          (gas_u32p)(A + (size_t)(m0 + row) * lda + k0 + kcs * 8),
          (las_u32p)(ldsA + chunk * 8), 16, 0, 0);
      __builtin_amdgcn_global_load_lds(
          (gas_u32p)(B + (size_t)(n0 + row) * ldb + k0 + kcs * 8),
          (las_u32p)(ldsB + chunk * 8), 16, 0, 0);
    }
    __syncthreads();   // compiler emits vmcnt(0) drain: staged tiles visible
    #pragma unroll
    for (int s = 0; s < 2; ++s) {
      // swizzled read column: chunk (s*4+lq) of row (..+lrow) sits at slot ^(lrow&7)
      int cbyteoff = (((s * 4 + lq) ^ (lrow & 7)) * 8);
      bf16x8 af[4], bfr[4];
      #pragma unroll
      for (int f = 0; f < 4; ++f)
        af[f] = *(const bf16x8*)(ldsA + (wm * 64 + f * 16 + lrow) * BK + cbyteoff);
      #pragma unroll
      for (int f = 0; f < 4; ++f)
        bfr[f] = *(const bf16x8*)(ldsB + (wn * 64 + f * 16 + lrow) * BK + cbyteoff);
      #pragma unroll
      for (int fi = 0; fi < 4; ++fi)
        #pragma unroll
        for (int fj = 0; fj < 4; ++fj)
          acc[fi][fj] = __builtin_amdgcn_mfma_f32_16x16x32_bf16(af[fi], bfr[fj], acc[fi][fj], 0, 0, 0);
    }
  }
}

// Latent GEMM body ([4096x1024]@[4096x1024]^T, tanh(+bias), bf16 store).
__device__ __forceinline__ void latent_body(int id, const unsigned short* __restrict__ ctxb,
                                            const unsigned short* __restrict__ lwb,
                                            const float* __restrict__ lb,
                                            unsigned short* __restrict__ latent,
                                            unsigned short* lds) {
  f32x4 zero = {0.f, 0.f, 0.f, 0.f};
  f32x4 acc[4][4];
  #pragma unroll
  for (int i = 0; i < 4; ++i)
    #pragma unroll
    for (int j = 0; j < 4; ++j) acc[i][j] = zero;
  int xcd = id & 7, idx = id >> 3;
  int ctl = idx & 3, by = idx >> 2;
  int m0 = by * BM, n0 = (xcd * 4 + ctl) * BN;
  gemm_mainloop(ctxb, lwb, 1024, 1024, m0, n0, 1024 / BK, lds, lds + BM * BK, acc);

  const int lane = threadIdx.x & 63, wave = threadIdx.x >> 6;
  const int wm = wave & 1, wn = wave >> 1, lrow = lane & 15, lq = lane >> 4;
  #pragma unroll
  for (int fi = 0; fi < 4; ++fi)
    #pragma unroll
    for (int fj = 0; fj < 4; ++fj) {
      int gcol = n0 + wn * 64 + fj * 16 + lrow;
      float bias = lb[gcol];
      #pragma unroll
      for (int r = 0; r < 4; ++r) {
        int grow = m0 + wm * 64 + fi * 16 + lq * 4 + r;
        float v = tanhf(acc[fi][fj][r] + bias);
        latent[(size_t)grow * 4096 + gcol] = f2bf(v);
      }
    }
}

// Fused latent + priors: even blocks latent (id=l>>1, 0..1023), odd priors.
__global__ __launch_bounds__(256, 4)
void k_lat_pri(const unsigned short* __restrict__ ctxb, const unsigned short* __restrict__ lwb,
               const float* __restrict__ lb, unsigned short* __restrict__ latent,
               const float* __restrict__ ctx, const float* __restrict__ pw,
               const float* __restrict__ pb, float* __restrict__ priors) {
  __shared__ unsigned short lds[(BM + BN) * BK];
  int l = blockIdx.x;
  if (l & 1) { priors_body(l >> 1, ctx, pw, pb, priors); return; }
  latent_body(l >> 1, ctxb, lwb, lb, latent, lds);
}

// Decoder pass1 body over row-chunk [m_base,..): logits tile -> exp(fp16) ->
// Z from ROUNDED values (atomicAdd) -> P tile staged via LDS XOR swizzle ->
// coalesced 16B/lane P stores (chunk-local rows).
__device__ __forceinline__ void dec_pass1_body(int id, const unsigned short* __restrict__ latb,
                                               const unsigned short* __restrict__ dwb,
                                               const float* __restrict__ db,
                                               float* __restrict__ Z,
                                               _Float16* __restrict__ P, int m_base,
                                               unsigned short* lds) {
  int xcd = id & 7, idx = id >> 3;
  int ctl = idx % 10, by = idx / 10;
  int n0 = (xcd * 10 + ctl) * BN, m0 = m_base + by * BM;
  if (n0 >= 10000) return;   // pure-pad tile, exits before any barrier

  f32x4 zero = {0.f, 0.f, 0.f, 0.f};
  f32x4 acc[4][4];
  #pragma unroll
  for (int i = 0; i < 4; ++i)
    #pragma unroll
    for (int j = 0; j < 4; ++j) acc[i][j] = zero;
  gemm_mainloop(latb, dwb, 512, 512, m0, n0, 512 / BK, lds, lds + BM * BK, acc);

  const int lane = threadIdx.x & 63, wave = threadIdx.x >> 6;
  const int wm = wave & 1, wn = wave >> 1, lrow = lane & 15, lq = lane >> 4;

  __syncthreads();                  // mainloop LDS reads done in all waves before reuse
  _Float16* ldsP = (_Float16*)lds;  // 128x128 fp16 = 32 KB

  float rowsum[4][4];
  #pragma unroll
  for (int fi = 0; fi < 4; ++fi)
    #pragma unroll
    for (int r = 0; r < 4; ++r) rowsum[fi][r] = 0.f;
  #pragma unroll
  for (int fj = 0; fj < 4; ++fj) {
    int gcol = n0 + wn * 64 + fj * 16 + lrow;
    bool valid = gcol < 10000;
    float bias = valid ? db[gcol] : 0.f;
    #pragma unroll
    for (int fi = 0; fi < 4; ++fi)
      #pragma unroll
      for (int r = 0; r < 4; ++r) {
        float e = __expf(acc[fi][fj][r] + bias);
        _Float16 h = (_Float16)e;
        if (valid) rowsum[fi][r] += (float)h;
        int row_l = wm * 64 + fi * 16 + lq * 4 + r;
        int col_l = wn * 64 + fj * 16 + lrow;
        ldsP[row_l * 128 + (((col_l >> 3) ^ (row_l & 7)) << 3) + (col_l & 7)] = h;
      }
  }

  __syncthreads();
  #pragma unroll
  for (int it = 0; it < 8; ++it) {
    int chunk = it * 256 + threadIdx.x;   // 0..2047 16B chunks = 32 KB
    int row_l = chunk >> 4, c8 = chunk & 15;
    int slot = c8 ^ (row_l & 7);
    uint4 v = *(const uint4*)((const char*)lds + row_l * 256 + slot * 16);
    *(uint4*)(P + (size_t)(by * BM + row_l) * 10112 + n0 + c8 * 8) = v;
  }

  #pragma unroll
  for (int fi = 0; fi < 4; ++fi)
    #pragma unroll
    for (int r = 0; r < 4; ++r) {
      float s = rowsum[fi][r];
      s += __shfl_xor(s, 1); s += __shfl_xor(s, 2);
      s += __shfl_xor(s, 4); s += __shfl_xor(s, 8);
      if (lrow == 0) atomicAdd(&Z[m0 + wm * 64 + fi * 16 + lq * 4 + r], s);
    }
}

// Combine body: out[t,c] = sum_k (prior/Z)[t,k] * P[tl*8+k][c]; flattened grid
// id in [0, tokens*5): tl = id/5, col-group = id%5.
__device__ __forceinline__ void combine_body(int id, const _Float16* __restrict__ P,
                                             const float* __restrict__ priors,
                                             const float* __restrict__ Z,
                                             float* __restrict__ out, int t_base) {
  int tl = id / 5, yg = id % 5;
  int t = t_base + tl;
  const _Float16* base = P + (size_t)tl * 8 * 10112;
  float w[8];
  #pragma unroll
  for (int k = 0; k < 8; ++k) w[k] = priors[t * 8 + k] / Z[t * 8 + k];
  int c8 = yg * 256 + threadIdx.x;
  if (c8 < 1250) {
    int c = c8 * 8;
    float s[8] = {0.f, 0.f, 0.f, 0.f, 0.f, 0.f, 0.f, 0.f};
    #pragma unroll
    for (int k = 0; k < 8; ++k) {
      f16x8 v = *(const f16x8*)(base + (size_t)k * 10112 + c);
      #pragma unroll
      for (int j = 0; j < 8; ++j) s[j] += w[k] * (float)v[j];
    }
    float4 o0 = {s[0], s[1], s[2], s[3]};
    float4 o1 = {s[4], s[5], s[6], s[7]};
    *(float4*)(out + (size_t)t * 10000 + c) = o0;
    *(float4*)(out + (size_t)t * 10000 + c + 4) = o1;
  }
}

// Fat dispatch: n_p1 pass1 blocks (chunk at m_base, write Pw) + n_cb combine
// blocks (chunk at t_base, read Pr). When both present (n_p1==n_cb), blocks
// interleave even/odd so memory-bound combine fills pass1's idle BW and
// ramp/drain slots.
__global__ __launch_bounds__(256, 4)
void k_dec_fat(const unsigned short* __restrict__ latb, const unsigned short* __restrict__ dwb,
               const float* __restrict__ db, float* __restrict__ Z,
               _Float16* __restrict__ Pw, int m_base,
               const _Float16* __restrict__ Pr, const float* __restrict__ priors,
               float* __restrict__ out, int t_base,
               int n_p1, int n_cb) {
  __shared__ unsigned short lds[(BM + BN) * BK];
  int l = blockIdx.x;
  bool cb; int id;
  if (n_p1 == 0)      { cb = true;  id = l; }
  else if (n_cb == 0) { cb = false; id = l; }
  else                { cb = (l & 1); id = l >> 1; }
  if (cb) { combine_body(id, Pr, priors, Z, out, t_base); return; }
  dec_pass1_body(id, latb, dwb, db, Z, Pw, m_base, lds);
}

// ---- standalone kernels for reduced-workspace fallback paths ----

template<int STORE>
__global__ __launch_bounds__(256, 4)
void k_dec_pass1(const unsigned short* __restrict__ latb, const unsigned short* __restrict__ dwb,
                 const float* __restrict__ db, float* __restrict__ Z,
                 _Float16* __restrict__ P, int m_base) {
  __shared__ unsigned short lds[(BM + BN) * BK];
  if (STORE) {
    dec_pass1_body(blockIdx.x, latb, dwb, db, Z, P, m_base, lds);
    return;
  }
  int l = blockIdx.x;
  int xcd = l & 7, idx = l >> 3;
  int ctl = idx % 10, by = idx / 10;
  int n0 = (xcd * 10 + ctl) * BN, m0 = m_base + by * BM;
  if (n0 >= 10000) return;
  f32x4 zero = {0.f, 0.f, 0.f, 0.f};
  f32x4 acc[4][4];
  #pragma unroll
  for (int i = 0; i < 4; ++i)
    #pragma unroll
    for (int j = 0; j < 4; ++j) acc[i][j] = zero;
  gemm_mainloop(latb, dwb, 512, 512, m0, n0, 512 / BK, lds, lds + BM * BK, acc);
  const int lane = threadIdx.x & 63, wave = threadIdx.x >> 6;
  const int wm = wave & 1, wn = wave >> 1, lrow = lane & 15, lq = lane >> 4;
  float rowsum[4][4];
  #pragma unroll
  for (int fi = 0; fi < 4; ++fi)
    #pragma unroll
    for (int r = 0; r < 4; ++r) rowsum[fi][r] = 0.f;
  #pragma unroll
  for (int fj = 0; fj < 4; ++fj) {
    int gcol = n0 + wn * 64 + fj * 16 + lrow;
    bool valid = gcol < 10000;
    float bias = valid ? db[gcol] : 0.f;
    #pragma unroll
    for (int fi = 0; fi < 4; ++fi)
      #pragma unroll
      for (int r = 0; r < 4; ++r)
        if (valid) rowsum[fi][r] += __expf(acc[fi][fj][r] + bias);
  }
  #pragma unroll
  for (int fi = 0; fi < 4; ++fi)
    #pragma unroll
    for (int r = 0; r < 4; ++r) {
      float s = rowsum[fi][r];
      s += __shfl_xor(s, 1); s += __shfl_xor(s, 2);
      s += __shfl_xor(s, 4); s += __shfl_xor(s, 8);
      if (lrow == 0) atomicAdd(&Z[m0 + wm * 64 + fi * 16 + lq * 4 + r], s);
    }
}

__global__ __launch_bounds__(256)
void k_combine(const _Float16* __restrict__ P, const float* __restrict__ priors,
               const float* __restrict__ Z, float* __restrict__ out, int t_base) {
  combine_body(blockIdx.y + 5 * blockIdx.x, P, priors, Z, out, t_base);
}

// Decoder pass 2 (deep fallback, ws too small for any P buffer).
__global__ __launch_bounds__(256, 4)
void k_dec_pass2(const unsigned short* __restrict__ latb, const unsigned short* __restrict__ dwb,
                 const float* __restrict__ db, const float* __restrict__ priors,
                 const float* __restrict__ Z, float* __restrict__ out) {
  __shared__ unsigned short lds[(BM + BN) * BK];
  int l = blockIdx.x;
  int xcd = l & 7, idx = l >> 3;
  int ctl = idx % 10, by = idx / 10;
  int n0 = (xcd * 10 + ctl) * BN, m0 = by * BM;
  if (n0 >= 10000) return;

  f32x4 zero = {0.f, 0.f, 0.f, 0.f};
  f32x4 acc[4][4];
  #pragma unroll
  for (int i = 0; i < 4; ++i)
    #pragma unroll
    for (int j = 0; j < 4; ++j) acc[i][j] = zero;
  gemm_mainloop(latb, dwb, 512, 512, m0, n0, 512 / BK, lds, lds + BM * BK, acc);

  const int tid = threadIdx.x;
  const int lane = tid & 63, wave = tid >> 6;
  const int wm = wave & 1, wn = wave >> 1, lrow = lane & 15, lq = lane >> 4;

  __syncthreads();
  float* ldsO = (float*)lds;

  #pragma unroll
  for (int fi = 0; fi < 4; ++fi) {
    int rbase = m0 + wm * 64 + fi * 16 + lq * 4;
    float w[4];
    #pragma unroll
    for (int r = 0; r < 4; ++r) w[r] = priors[rbase + r] / Z[rbase + r];
    #pragma unroll
    for (int fj = 0; fj < 4; ++fj) {
      int gcol = n0 + wn * 64 + fj * 16 + lrow;
      float bias = (gcol < 10000) ? db[gcol] : 0.f;
      float part = 0.f;
      #pragma unroll
      for (int r = 0; r < 4; ++r) part += w[r] * __expf(acc[fi][fj][r] + bias);
      float tok = part + __shfl_xor(part, 16);
      if (!(lq & 1)) {
        int tl = wm * 8 + fi * 2 + (lq >> 1);
        int cl = wn * 64 + fj * 16 + lrow;
        ldsO[tl * 128 + cl] = tok;
      }
    }
  }
  __syncthreads();
  int tok0 = m0 >> 3;
  #pragma unroll
  for (int it = 0; it < 2; ++it) {
    int f = it * 256 + tid;
    int tl = f >> 5, c4 = f & 31;
    int col = n0 + c4 * 4;
    if (col < 10000)
      *(float4*)(out + (size_t)(tok0 + tl) * 10000 + col) = *(float4*)(ldsO + tl * 128 + c4 * 4);
  }
}

extern "C" void kernel_launch(void* const* d_in, const int* in_sizes, int n_in,
                              void* d_out, int out_size, void* d_ws, size_t ws_size,
                              hipStream_t stream) {
  const float* ctx = (const float*)d_in[0];  // [4096,1024]
  const float* pw  = (const float*)d_in[1];  // [8,1024]
  const float* pb  = (const float*)d_in[2];  // [8]
  const float* lw  = (const float*)d_in[3];  // [4096,1024]
  const float* lb  = (const float*)d_in[4];  // [4096]
  const float* dw  = (const float*)d_in[5];  // [10000,512]
  const float* db  = (const float*)d_in[6];  // [10000]
  float* out = (float*)d_out;

  char* ws = (char*)d_ws;
  unsigned short* ctxb = (unsigned short*)ws;                // 8,388,608 B
  unsigned short* lwb  = (unsigned short*)(ws + 8388608);    // 8,388,608 B
  unsigned short* dwb  = (unsigned short*)(ws + 16777216);   // 10112*512*2 = 10,354,688 B
  unsigned short* latb = (unsigned short*)(ws + 27131904);   // 32768*512*2 = 33,554,432 B
  float* priors        = (float*)(ws + 60686336);            // 131,072 B
  float* Z             = (float*)(ws + 60817408);            // 131,072 B
  const size_t WS_BASE = 60948480ull;
  const size_t CHUNK_BYTES = 8192ull * 10112ull * 2ull;      // 165,675,008 B
  _Float16* pex[2] = { (_Float16*)(ws + WS_BASE),
                       (_Float16*)(ws + WS_BASE + CHUNK_BYTES) };

  size_t avail = ws_size > WS_BASE ? ws_size - WS_BASE : 0;
  int mode = (avail >= 2 * CHUNK_BYTES) ? 2 : (avail >= CHUNK_BYTES ? 1 : 0);

  k_cvt_all<<<13192, 256, 0, stream>>>((const float4*)ctx, (ushort4*)ctxb,
                                       (const float4*)lw, (ushort4*)lwb,
                                       (const float4*)dw, (ushort4*)dwb);
  hipMemsetAsync(dwb + (size_t)10000 * 512, 0, (size_t)112 * 512 * 2, stream);  // zero pad rows
  hipMemsetAsync(Z, 0, 32768 * 4, stream);

  k_lat_pri<<<2048, 256, 0, stream>>>(ctxb, lwb, lb, latb, ctx, pw, pb, priors);

  if (mode == 2) {
    // 4 chunks of 8192 rows; 5 dispatches:
    // P0 | P1+C0 | P2+C1 | P3+C2 | C3   (ping-pong P buffers)
    for (int ch = 0; ch < 5; ++ch) {
      int n_p1 = (ch < 4) ? 5120 : 0;
      int n_cb = (ch > 0) ? 5120 : 0;
      k_dec_fat<<<n_p1 + n_cb, 256, 0, stream>>>(
          latb, dwb, db, Z,
          (ch < 4) ? pex[ch & 1] : nullptr, ch * 8192,
          (ch > 0) ? pex[(ch - 1) & 1] : nullptr, priors,
          out, (ch - 1) * 1024,
          n_p1, n_cb);
    }
  } else if (mode == 1) {
    for (int ms = 0; ms < 32768; ms += 8192) {
      k_dec_pass1<1><<<5120, 256, 0, stream>>>(latb, dwb, db, Z, pex[0], ms);
      k_combine<<<dim3(1024, 5), 256, 0, stream>>>(pex[0], priors, Z, out, ms / 8);
    }
  } else {
    k_dec_pass1<0><<<20480, 256, 0, stream>>>(latb, dwb, db, Z, nullptr, 0);
    k_dec_pass2<<<20480, 256, 0, stream>>>(latb, dwb, db, priors, Z, out);
  }
}